// Round 3
// baseline (2361.677 us; speedup 1.0000x reference)
//
#include <hip/hip_runtime.h>
#include <hip/hip_fp16.h>
#include <cstdint>

typedef _Float16 f16x8 __attribute__((ext_vector_type(8)));
typedef _Float16 half2_t __attribute__((ext_vector_type(2)));
typedef float f32x4 __attribute__((ext_vector_type(4)));
typedef uint32_t u32x4 __attribute__((ext_vector_type(4)));
typedef uint32_t u32x2 __attribute__((ext_vector_type(2)));

// Sizes: B=64, T=1024, IN=256, HID=256. Packed gate column c in [0,1024):
// unit u = c>>2, gate g = c&3 (0=i,1=f,2=o,3=c).
// Weight K-pair row kp in [0,128) packs Wh rows 2kp,2kp+1.
// Rows 0..103 (26 quads) -> VGPRs. Rows 104..127 (12 pairs) -> LDS.

// Workspace layout (bytes)
#define XG_OFF    0ULL
#define XG_BYTES  134217728ULL   // xgp[b*1024+t][512] u32: lo half = col w, hi = col 512+w
#define AP_OFF    (XG_OFF + XG_BYTES)
#define AP_BYTES  33554432ULL
#define BP_OFF    (AP_OFF + AP_BYTES)
#define BP_BYTES  524288ULL
#define WHPQ_OFF  (BP_OFF + BP_BYTES)
#define WHPQ_BYTES 425984ULL     // [26 quads][1024 cols][4] u32
#define WLG_OFF   (WHPQ_OFF + WHPQ_BYTES)
#define WLG_BYTES 98304ULL       // [12 jp][1024 cols][2] u32  (rows 104..127)
#define BIAS_OFF  (WLG_OFF + WLG_BYTES)

__device__ inline half2_t u2h2(uint32_t v) {
    union { uint32_t u; half2_t h; } c; c.u = v; return c.h;
}
#define FD(W, H, A) __builtin_amdgcn_fdot2(u2h2(W), u2h2(H), (A), false)
#define QB(v, pat) __int_as_float(__builtin_amdgcn_ds_swizzle(__float_as_int(v), (pat)))

#define QLIST(F) F(0) F(1) F(2) F(3) F(4) F(5) F(6) F(7) F(8) F(9) F(10) F(11) F(12) \
                 F(13) F(14) F(15) F(16) F(17) F(18) F(19) F(20) F(21) F(22) F(23) F(24) F(25)

// ---------------- Phase 0: pack weights (reg-quad + LDS-pair layouts) + B frags + bias --
__global__ void pack_weights(const float* __restrict__ Wi, const float* __restrict__ Wf,
                             const float* __restrict__ Wo, const float* __restrict__ Wc,
                             const float* __restrict__ bi, const float* __restrict__ bf,
                             const float* __restrict__ bo, const float* __restrict__ bc,
                             uint32_t* __restrict__ WhpQ, uint32_t* __restrict__ WlG,
                             __half* __restrict__ Bp, float* __restrict__ bias_eff)
{
    int tidg = blockIdx.x * blockDim.x + threadIdx.x;
    if (tidg < 106496) {
        // WhpQ[((q*1024)+c)*4 + i] = pack(Wg[2kp][u], Wg[2kp+1][u]), kp = q*4+i
        int i = tidg & 3;
        int c = (tidg >> 2) & 1023;
        int q = tidg >> 12;
        int kp = q * 4 + i;
        int u = c >> 2, g = c & 3;
        const float* W = (g == 0) ? Wi : (g == 1) ? Wf : (g == 2) ? Wo : Wc;
        union { uint32_t u32; __half h[2]; } pk;
        pk.h[0] = __float2half(W[(2 * kp) * 256 + u]);
        pk.h[1] = __float2half(W[(2 * kp + 1) * 256 + u]);
        WhpQ[tidg] = pk.u32;
    } else if (tidg < 131072) {
        // WlG[((jp*1024)+c)*2 + k] : kp = 104 + 2*jp + k
        int e = tidg - 106496;
        int k = e & 1;
        int c = (e >> 1) & 1023;
        int jp = e >> 11;
        int kp = 104 + 2 * jp + k;
        int u = c >> 2, g = c & 3;
        const float* W = (g == 0) ? Wi : (g == 1) ? Wf : (g == 2) ? Wo : Wc;
        union { uint32_t u32; __half h[2]; } pk;
        pk.h[0] = __float2half(W[(2 * kp) * 256 + u]);
        pk.h[1] = __float2half(W[(2 * kp + 1) * 256 + u]);
        WlG[e] = pk.u32;
    } else if (tidg < 131072 + 262144) {
        // Bp[((n*8+kk)*64+l)*8+i] = Wx_eff[k = kk*32+(l>>4)*8+i][c = n*16+(l&15)]
        int beta = tidg - 131072;
        int i = beta & 7;
        int l = (beta >> 3) & 63;
        int kk = (beta >> 9) & 7;
        int n = beta >> 12;
        int c = n * 16 + (l & 15);
        int u = c >> 2, g = c & 3;
        int k = kk * 32 + (l >> 4) * 8 + i;
        const float* W = (g == 0) ? Wi : (g == 1) ? Wf : (g == 2) ? Wo : Wc;
        Bp[beta] = __float2half(W[(256 + k) * 256 + u]);
    } else if (tidg < 131072 + 262144 + 1024) {
        int c = tidg - (131072 + 262144);
        int g = c & 3;
        const float* bb = (g == 0) ? bi : (g == 1) ? bf : (g == 2) ? bo : bc;
        bias_eff[c] = bb[c >> 2];
    }
}

// ---------------- Phase 0b: pack x into A fragments ----------------
__global__ void pack_a(const float* __restrict__ x, __half* __restrict__ Ap)
{
    int t = blockIdx.x * blockDim.x + threadIdx.x;
    int l  = t & 63;
    int kk = (t >> 6) & 7;
    int m  = t >> 9;
    int row = m * 16 + (l & 15);
    int k0  = kk * 32 + (l >> 4) * 8;
    const float* src = x + (size_t)row * 256 + k0;
    f16x8 v;
#pragma unroll
    for (int i = 0; i < 8; ++i) v[i] = (_Float16)src[i];
    *reinterpret_cast<f16x8*>(Ap + (size_t)t * 8) = v;
}

// ---------------- Phase 1: xg = x @ Wx + bias (u32-paired output layout) ----------------
__global__ __launch_bounds__(256) void gemm_xg(const __half* __restrict__ Ap,
                                               const __half* __restrict__ Bp,
                                               const float* __restrict__ bias_eff,
                                               __half* __restrict__ xgh)
{
    int wave = threadIdx.x >> 6;
    int lane = threadIdx.x & 63;
    int mtile = blockIdx.x * 4 + wave;
    int ntbase = blockIdx.y * 16;

    f16x8 a[8];
#pragma unroll
    for (int kk = 0; kk < 8; ++kk)
        a[kk] = *reinterpret_cast<const f16x8*>(Ap + ((size_t)(mtile * 8 + kk) * 64 + lane) * 8);

    int col_lo = lane & 15;
    int rgrp = lane >> 4;
#pragma unroll 1
    for (int j = 0; j < 16; ++j) {
        int nt = ntbase + j;
        int c = nt * 16 + col_lo;
        float bb = bias_eff[c];
        f32x4 acc = {bb, bb, bb, bb};
#pragma unroll
        for (int kk = 0; kk < 8; ++kk) {
            f16x8 bfr = *reinterpret_cast<const f16x8*>(Bp + ((size_t)(nt * 8 + kk) * 64 + lane) * 8);
            acc = __builtin_amdgcn_mfma_f32_16x16x32_f16(a[kk], bfr, acc, 0, 0, 0);
        }
        int hidx = ((c & 511) << 1) | (c >> 9);   // paired-u32 half index
#pragma unroll
        for (int r = 0; r < 4; ++r) {
            int row = mtile * 16 + rgrp * 4 + r;
            xgh[(size_t)row * 1024 + hidx] = __float2half(acc[r]);
        }
    }
}

// ---------------- Phase 2: sequential recurrence, ONE WG per batch ----------------
// 64 WGs x 512 threads (8 waves = 2/SIMD, 1 block/CU). Thread tid owns cols tid and
// 512+tid. 208 weight VGPRs as NAMED u32x4 vars (static access only) + 24 rows in LDS.
__global__ __launch_bounds__(512, 2) void lstm_rec(
    const uint32_t* __restrict__ xgp,
    const uint32_t* __restrict__ WhpQ,
    const uint32_t* __restrict__ WlG,
    float* __restrict__ out)
{
    const int b = blockIdx.x;
    const int tid = threadIdx.x;
    const int g = tid & 3;
    const int ul = tid >> 2;          // u0 = ul, u1 = 128 + ul

    __shared__ uint32_t WlLDS[24576];             // 96 KB: [12][1024][2]
    __shared__ alignas(16) uint32_t h2[2][128];   // 1 KB packed-f16 h, double-buffered

    for (int i = tid; i < 24576; i += 512) WlLDS[i] = WlG[i];
    if (tid < 128) { h2[0][tid] = 0u; h2[1][tid] = 0u; }

    // ---- register-resident weights: named vars, fully static ----
#define DECLW(q) u32x4 w0_##q, w1_##q;
    QLIST(DECLW)
#undef DECLW
#define LOADW(q) \
    w0_##q = *reinterpret_cast<const u32x4*>(WhpQ + (((q) * 1024) + tid) * 4); \
    w1_##q = *reinterpret_cast<const u32x4*>(WhpQ + (((q) * 1024) + 512 + tid) * 4);
    QLIST(LOADW)
#undef LOADW
    __syncthreads();

    const float kAct = (g == 3) ? 2.88539008f : -1.44269504f;  // tanh : sigmoid (exp2-based)
    const float aAct = (g == 3) ? -2.0f : 1.0f;
    const float bAct = (g == 3) ? 1.0f : 0.0f;

    float c0s = 0.f, c1s = 0.f;
    const uint32_t* xrow = xgp + (size_t)b * 1024 * 512 + tid;
    uint32_t xw = xrow[0];                         // 1-step-ahead prefetch

    for (int t = 0; t < 1024; ++t) {
        const uint32_t* hr = h2[t & 1];
        int tn = (t < 1023) ? (t + 1) : 1023;
        uint32_t xw_next = xrow[(size_t)tn * 512];

        float a00 = 0.f, a01 = 0.f, a10 = 0.f, a11 = 0.f;
#define DOTQ(q) { \
        u32x4 hq = *reinterpret_cast<const u32x4*>(hr + (q) * 4); \
        a00 = FD(w0_##q[0], hq[0], a00); a10 = FD(w1_##q[0], hq[0], a10); \
        a01 = FD(w0_##q[1], hq[1], a01); a11 = FD(w1_##q[1], hq[1], a11); \
        a00 = FD(w0_##q[2], hq[2], a00); a10 = FD(w1_##q[2], hq[2], a10); \
        a01 = FD(w0_##q[3], hq[3], a01); a11 = FD(w1_##q[3], hq[3], a11); }
        QLIST(DOTQ)
#undef DOTQ

        // tail rows 104..127 from LDS (per-col row-pairs, b64 reads)
        {
            u32x4 hT0 = *reinterpret_cast<const u32x4*>(hr + 104);
            u32x4 hT1 = *reinterpret_cast<const u32x4*>(hr + 108);
            u32x4 hT2 = *reinterpret_cast<const u32x4*>(hr + 112);
            u32x4 hT3 = *reinterpret_cast<const u32x4*>(hr + 116);
            u32x4 hT4 = *reinterpret_cast<const u32x4*>(hr + 120);
            u32x4 hT5 = *reinterpret_cast<const u32x4*>(hr + 124);
#define TAILJP(jp, HA, HB) { \
            u32x2 wl0 = *reinterpret_cast<const u32x2*>(&WlLDS[((jp) * 1024 + tid) * 2]); \
            u32x2 wl1 = *reinterpret_cast<const u32x2*>(&WlLDS[((jp) * 1024 + 512 + tid) * 2]); \
            a00 = FD(wl0[0], HA, a00); a01 = FD(wl0[1], HB, a01); \
            a10 = FD(wl1[0], HA, a10); a11 = FD(wl1[1], HB, a11); }
            TAILJP(0,  hT0[0], hT0[1])  TAILJP(1,  hT0[2], hT0[3])
            TAILJP(2,  hT1[0], hT1[1])  TAILJP(3,  hT1[2], hT1[3])
            TAILJP(4,  hT2[0], hT2[1])  TAILJP(5,  hT2[2], hT2[3])
            TAILJP(6,  hT3[0], hT3[1])  TAILJP(7,  hT3[2], hT3[3])
            TAILJP(8,  hT4[0], hT4[1])  TAILJP(9,  hT4[2], hT4[3])
            TAILJP(10, hT5[0], hT5[1])  TAILJP(11, hT5[2], hT5[3])
#undef TAILJP
        }

        union { uint32_t u; __half h[2]; } xc; xc.u = xw;
        float pre0 = (a00 + a01) + __half2float(xc.h[0]);
        float pre1 = (a10 + a11) + __half2float(xc.h[1]);

        float r0 = __builtin_amdgcn_rcpf(1.f + __builtin_amdgcn_exp2f(kAct * pre0));
        float r1 = __builtin_amdgcn_rcpf(1.f + __builtin_amdgcn_exp2f(kAct * pre1));
        float gv0 = fmaf(aAct, r0, bAct);
        float gv1 = fmaf(aAct, r1, bAct);

        // quad gate exchange (lanes 4u..4u+3 hold i,f,o,c of unit u)
        float i0 = QB(gv0, 0x8000), f0 = QB(gv0, 0x8055), o0 = QB(gv0, 0x80AA), q0 = QB(gv0, 0x80FF);
        float i1 = QB(gv1, 0x8000), f1 = QB(gv1, 0x8055), o1 = QB(gv1, 0x80AA), q1 = QB(gv1, 0x80FF);

        c0s = fmaf(f0, c0s, i0 * q0);
        c1s = fmaf(f1, c1s, i1 * q1);
        float t0 = fmaf(-2.f, __builtin_amdgcn_rcpf(1.f + __builtin_amdgcn_exp2f(2.88539008f * c0s)), 1.f);
        float t1 = fmaf(-2.f, __builtin_amdgcn_rcpf(1.f + __builtin_amdgcn_exp2f(2.88539008f * c1s)), 1.f);
        float h0 = o0 * t0;
        float h1 = o1 * t1;

        __half* hw = reinterpret_cast<__half*>(h2[(t + 1) & 1]);
        if (g == 0)      hw[ul] = __float2half(h0);
        else if (g == 2) hw[128 + ul] = __float2half(h1);
        else if (g == 1) {
            float* orow = out + ((size_t)t * 64 + b) * 256;
            orow[ul] = h0;
            orow[128 + ul] = h1;
        }
        __syncthreads();
        xw = xw_next;
    }
}

// ---------------- launch ----------------
extern "C" void kernel_launch(void* const* d_in, const int* in_sizes, int n_in,
                              void* d_out, int out_size, void* d_ws, size_t ws_size,
                              hipStream_t stream)
{
    const float* x  = (const float*)d_in[0];
    const float* Wi = (const float*)d_in[1];
    const float* bi = (const float*)d_in[2];
    const float* Wf = (const float*)d_in[3];
    const float* bf = (const float*)d_in[4];
    const float* Wo = (const float*)d_in[5];
    const float* bo = (const float*)d_in[6];
    const float* Wc = (const float*)d_in[7];
    const float* bc = (const float*)d_in[8];

    char* ws = (char*)d_ws;
    __half*   xgh      = (__half*)(ws + XG_OFF);
    uint32_t* xgp      = (uint32_t*)(ws + XG_OFF);
    __half*   Ap       = (__half*)(ws + AP_OFF);
    __half*   Bp       = (__half*)(ws + BP_OFF);
    uint32_t* WhpQ     = (uint32_t*)(ws + WHPQ_OFF);
    uint32_t* WlG      = (uint32_t*)(ws + WLG_OFF);
    float*    bias_eff = (float*)(ws + BIAS_OFF);

    pack_weights<<<1540, 256, 0, stream>>>(Wi, Wf, Wo, Wc, bi, bf, bo, bc, WhpQ, WlG, Bp, bias_eff);
    pack_a<<<8192, 256, 0, stream>>>(x, Ap);
    gemm_xg<<<dim3(1024, 4), 256, 0, stream>>>(Ap, Bp, bias_eff, xgh);
    lstm_rec<<<64, 512, 0, stream>>>(xgp, WhpQ, WlG, (float*)d_out);
}